// Round 1
// baseline (408.176 us; speedup 1.0000x reference)
//
#include <hip/hip_runtime.h>

// Fused: LN -> QKV proj -> 8-head attention (flash) -> out proj -> LN
// Shapes: x[4,64,256,512]; heads=8, dhead=64; all GEMMs bf16 MFMA, f32 accum.

#define DIM   512
#define DHEAD 64
#define HEADS 8
#define RLEN  256
#define TOK   65536   // 4*64*256 tokens

typedef __bf16 bf16;
typedef __bf16 bf16x8 __attribute__((ext_vector_type(8)));
typedef float  f32x4  __attribute__((ext_vector_type(4)));

__device__ __forceinline__ f32x4 mfma16(bf16x8 a, bf16x8 b, f32x4 c) {
  return __builtin_amdgcn_mfma_f32_16x16x32_bf16(a, b, c, 0, 0, 0);
}
__device__ __forceinline__ f32x4 fzero4() {
  f32x4 z; z[0] = z[1] = z[2] = z[3] = 0.f; return z;
}

// ---------------- K0: weights -> bf16, transposed to [N][K] ----------------
__global__ __launch_bounds__(256) void k_prep(
    const float* __restrict__ Wq, const float* __restrict__ Wkv,
    const float* __restrict__ Wout,
    bf16* __restrict__ wqt, bf16* __restrict__ wkvt, bf16* __restrict__ woutt) {
  int t = blockIdx.x * 256 + threadIdx.x;   // grid covers exactly 512*512
  int n = t >> 9, k = t & 511;
  wqt[t]   = (bf16)Wq[k * DIM + n];     // wqt[n][k] = W_q[k][n]
  woutt[t] = (bf16)Wout[k * DIM + n];   // woutt[n][k] = W_out[k][n]
  if (t < 128 * DIM) wkvt[t] = (bf16)Wkv[k * 128 + n];  // wkvt[n][k], n<128
}

// ---------------- K1: LN + Q/KV projection ----------------
// 64 token-rows per WG, 512 threads (8 waves). xn in XOR-swizzled LDS.
__global__ __launch_bounds__(512) void k_ln_qkv(
    const float* __restrict__ x, const float* __restrict__ gnorm,
    const bf16* __restrict__ wqt, const bf16* __restrict__ wkvt,
    bf16* __restrict__ qbuf, bf16* __restrict__ kbuf, bf16* __restrict__ vbuf) {
  __shared__ bf16 xn[64][DIM];  // element index XOR-swizzled by ((row&7)<<3)
  const int t = threadIdx.x;
  const int row0 = blockIdx.x * 64;

  { // ---- LayerNorm: 8 threads per row ----
    const int r = t >> 3, sub = t & 7;
    const float* xp = x + (size_t)(row0 + r) * DIM + sub * 64;
    float4 buf[16];
    float s = 0.f, sq = 0.f;
    #pragma unroll
    for (int i = 0; i < 16; ++i) {
      buf[i] = ((const float4*)xp)[i];
      s  += buf[i].x + buf[i].y + buf[i].z + buf[i].w;
      sq += buf[i].x*buf[i].x + buf[i].y*buf[i].y + buf[i].z*buf[i].z + buf[i].w*buf[i].w;
    }
    s += __shfl_xor(s, 1); sq += __shfl_xor(sq, 1);
    s += __shfl_xor(s, 2); sq += __shfl_xor(sq, 2);
    s += __shfl_xor(s, 4); sq += __shfl_xor(sq, 4);
    float mean = s * (1.f / 512.f);
    float var  = sq * (1.f / 512.f) - mean * mean;
    float rs   = rsqrtf(var + 1e-5f);
    const float* gp = gnorm + sub * 64;
    #pragma unroll
    for (int i = 0; i < 16; i += 2) {
      bf16x8 v8;
      #pragma unroll
      for (int u = 0; u < 2; ++u) {
        float4 bv = buf[i + u];
        v8[u*4+0] = (bf16)((bv.x - mean) * rs * gp[(i+u)*4+0]);
        v8[u*4+1] = (bf16)((bv.y - mean) * rs * gp[(i+u)*4+1]);
        v8[u*4+2] = (bf16)((bv.z - mean) * rs * gp[(i+u)*4+2]);
        v8[u*4+3] = (bf16)((bv.w - mean) * rs * gp[(i+u)*4+3]);
      }
      int c = sub * 64 + i * 4;
      *(bf16x8*)&xn[r][c ^ ((r & 7) << 3)] = v8;
    }
  }
  __syncthreads();

  // ---- GEMM: [64,512] x Wq^T[512n][512k] (+ Wkv^T[128n][512k]) ----
  const int wave = t >> 6, lane = t & 63;
  const int l15 = lane & 15, g = lane >> 4;
  const int n0 = wave * 64;
  f32x4 acc[4][4], acck[4];
  #pragma unroll
  for (int mi = 0; mi < 4; ++mi) {
    acck[mi] = fzero4();
    #pragma unroll
    for (int ni = 0; ni < 4; ++ni) acc[mi][ni] = fzero4();
  }
  const bf16* wq_base  = wqt  + (size_t)(n0 + l15) * DIM + g * 8;
  const bf16* wkv_base = wkvt + (size_t)(wave * 16 + l15) * DIM + g * 8;
  for (int kk = 0; kk < DIM; kk += 32) {
    bf16x8 a[4], bq[4], bkv;
    #pragma unroll
    for (int mi = 0; mi < 4; ++mi) {
      int rr = mi * 16 + l15;
      a[mi] = *(const bf16x8*)&xn[rr][(kk + g * 8) ^ ((rr & 7) << 3)];
    }
    #pragma unroll
    for (int ni = 0; ni < 4; ++ni)
      bq[ni] = *(const bf16x8*)(wq_base + (size_t)ni * 16 * DIM + kk);
    bkv = *(const bf16x8*)(wkv_base + kk);
    #pragma unroll
    for (int mi = 0; mi < 4; ++mi) {
      #pragma unroll
      for (int ni = 0; ni < 4; ++ni)
        acc[mi][ni] = mfma16(a[mi], bq[ni], acc[mi][ni]);
      acck[mi] = mfma16(a[mi], bkv, acck[mi]);
    }
  }
  // write q
  #pragma unroll
  for (int mi = 0; mi < 4; ++mi)
    #pragma unroll
    for (int ni = 0; ni < 4; ++ni)
      #pragma unroll
      for (int jj = 0; jj < 4; ++jj) {
        size_t row = (size_t)row0 + mi * 16 + g * 4 + jj;
        qbuf[row * DIM + n0 + ni * 16 + l15] = (bf16)acc[mi][ni][jj];
      }
  // write k/v (cols 0..63 -> k, 64..127 -> v)
  {
    int c = wave * 16 + l15;
    bf16* kvout = (wave < 4) ? (kbuf + c) : (vbuf + (c - 64));
    #pragma unroll
    for (int mi = 0; mi < 4; ++mi)
      #pragma unroll
      for (int jj = 0; jj < 4; ++jj) {
        size_t row = (size_t)row0 + mi * 16 + g * 4 + jj;
        kvout[row * DHEAD] = (bf16)acck[mi][jj];
      }
  }
}

// ---------------- K2: flash attention per (b*n, head) ----------------
// 512 threads (8 waves x 32 q-rows). Q in regs; K, V^T chunk-staged in LDS.
// Writes attention output in place over qbuf (own (bn,h) slice only).
__global__ __launch_bounds__(512) void k_attn(
    bf16* __restrict__ qbuf, const bf16* __restrict__ kbuf,
    const bf16* __restrict__ vbuf) {
  __shared__ bf16 lk[64][72];       // K chunk  [kvrow][d]
  __shared__ bf16 lvt[64][72];      // V^T chunk [d][kvrow]
  __shared__ bf16 lp[8][32][72];    // per-wave P tile [qrow][kvcol]
  const int t = threadIdx.x, wave = t >> 6, lane = t & 63;
  const int l15 = lane & 15, g = lane >> 4;
  const int bn = blockIdx.x >> 3, h = blockIdx.x & 7;
  const size_t tok0 = (size_t)bn * RLEN;
  const int m0 = wave * 32;

  bf16x8 aq[2][2];
  {
    const bf16* qb = qbuf + (tok0 + m0 + l15) * DIM + h * DHEAD + g * 8;
    #pragma unroll
    for (int mi = 0; mi < 2; ++mi)
      #pragma unroll
      for (int ks = 0; ks < 2; ++ks)
        aq[mi][ks] = *(const bf16x8*)(qb + (size_t)mi * 16 * DIM + ks * 32);
  }
  f32x4 o[2][4];
  float mrow[2][4], lrow[2][4];
  #pragma unroll
  for (int mi = 0; mi < 2; ++mi) {
    #pragma unroll
    for (int di = 0; di < 4; ++di) o[mi][di] = fzero4();
    #pragma unroll
    for (int jj = 0; jj < 4; ++jj) { mrow[mi][jj] = -1e30f; lrow[mi][jj] = 0.f; }
  }

  for (int j = 0; j < 4; ++j) {
    __syncthreads();
    { // stage K chunk (coalesced 16B) and V^T chunk (scalar transpose)
      const bf16* kc = kbuf + (tok0 + j * 64) * DHEAD;
      int r = t >> 3, c8 = (t & 7) * 8;
      *(bf16x8*)&lk[r][c8] = *(const bf16x8*)(kc + r * DHEAD + c8);
      const bf16* vc = vbuf + (tok0 + j * 64) * DHEAD;
      int c = t & 63;
      #pragma unroll
      for (int i = 0; i < 8; ++i) {
        int rr = (t >> 6) + i * 8;
        lvt[c][rr] = vc[rr * DHEAD + c];
      }
    }
    __syncthreads();

    // S = Q K^T for this chunk
    f32x4 s[2][4];
    #pragma unroll
    for (int mi = 0; mi < 2; ++mi)
      #pragma unroll
      for (int nj = 0; nj < 4; ++nj) s[mi][nj] = fzero4();
    #pragma unroll
    for (int ks = 0; ks < 2; ++ks) {
      bf16x8 bk[4];
      #pragma unroll
      for (int nj = 0; nj < 4; ++nj)
        bk[nj] = *(const bf16x8*)&lk[nj * 16 + l15][ks * 32 + g * 8];
      #pragma unroll
      for (int mi = 0; mi < 2; ++mi)
        #pragma unroll
        for (int nj = 0; nj < 4; ++nj)
          s[mi][nj] = mfma16(aq[mi][ks], bk[nj], s[mi][nj]);
    }

    // online softmax update (scale = 1/8 folds SCALE*PB_ALPHA)
    #pragma unroll
    for (int mi = 0; mi < 2; ++mi) {
      #pragma unroll
      for (int jj = 0; jj < 4; ++jj) {
        float s0 = s[mi][0][jj] * 0.125f;
        float s1 = s[mi][1][jj] * 0.125f;
        float s2 = s[mi][2][jj] * 0.125f;
        float s3 = s[mi][3][jj] * 0.125f;
        float cm = fmaxf(fmaxf(s0, s1), fmaxf(s2, s3));
        cm = fmaxf(cm, __shfl_xor(cm, 1));
        cm = fmaxf(cm, __shfl_xor(cm, 2));
        cm = fmaxf(cm, __shfl_xor(cm, 4));
        cm = fmaxf(cm, __shfl_xor(cm, 8));
        float mold = mrow[mi][jj];
        float mnew = fmaxf(mold, cm);
        float alpha = __expf(mold - mnew);
        mrow[mi][jj] = mnew;
        float p0 = __expf(s0 - mnew), p1 = __expf(s1 - mnew);
        float p2 = __expf(s2 - mnew), p3 = __expf(s3 - mnew);
        float ps = p0 + p1 + p2 + p3;
        ps += __shfl_xor(ps, 1); ps += __shfl_xor(ps, 2);
        ps += __shfl_xor(ps, 4); ps += __shfl_xor(ps, 8);
        lrow[mi][jj] = lrow[mi][jj] * alpha + ps;
        #pragma unroll
        for (int di = 0; di < 4; ++di) o[mi][di][jj] *= alpha;
        int prow = mi * 16 + g * 4 + jj;
        lp[wave][prow][ 0 + l15] = (bf16)p0;
        lp[wave][prow][16 + l15] = (bf16)p1;
        lp[wave][prow][32 + l15] = (bf16)p2;
        lp[wave][prow][48 + l15] = (bf16)p3;
      }
    }
    __syncthreads();

    // O += P V
    #pragma unroll
    for (int ks = 0; ks < 2; ++ks) {
      bf16x8 pa[2], bv[4];
      #pragma unroll
      for (int mi = 0; mi < 2; ++mi)
        pa[mi] = *(const bf16x8*)&lp[wave][mi * 16 + l15][ks * 32 + g * 8];
      #pragma unroll
      for (int di = 0; di < 4; ++di)
        bv[di] = *(const bf16x8*)&lvt[di * 16 + l15][ks * 32 + g * 8];
      #pragma unroll
      for (int mi = 0; mi < 2; ++mi)
        #pragma unroll
        for (int di = 0; di < 4; ++di)
          o[mi][di] = mfma16(pa[mi], bv[di], o[mi][di]);
    }
  }

  // epilogue: normalize, write back in place
  #pragma unroll
  for (int mi = 0; mi < 2; ++mi)
    #pragma unroll
    for (int jj = 0; jj < 4; ++jj) {
      float inv = 1.0f / lrow[mi][jj];
      size_t row = tok0 + m0 + mi * 16 + g * 4 + jj;
      #pragma unroll
      for (int di = 0; di < 4; ++di)
        qbuf[row * DIM + h * DHEAD + di * 16 + l15] = (bf16)(o[mi][di][jj] * inv);
    }
}

// ---------------- K3: out projection + LN ----------------
// 32 token-rows per WG, 512 threads (8 waves x 64 cols).
__global__ __launch_bounds__(512) void k_out_ln(
    const bf16* __restrict__ abuf, const bf16* __restrict__ woutt,
    const float* __restrict__ gout, float* __restrict__ out) {
  __shared__ bf16 la[32][DIM];     // XOR-swizzled
  __shared__ float2 part[32][8];
  __shared__ float2 stats[32];
  const int t = threadIdx.x, wave = t >> 6, lane = t & 63;
  const int l15 = lane & 15, g = lane >> 4;
  const size_t row0 = (size_t)blockIdx.x * 32;

  #pragma unroll
  for (int i = 0; i < 4; ++i) {
    int idx = t + i * 512;
    int r = idx >> 6, c = (idx & 63) * 8;
    *(bf16x8*)&la[r][c ^ ((r & 7) << 3)] =
        *(const bf16x8*)(abuf + (row0 + r) * DIM + c);
  }
  __syncthreads();

  const int n0 = wave * 64;
  f32x4 acc[2][4];
  #pragma unroll
  for (int mi = 0; mi < 2; ++mi)
    #pragma unroll
    for (int ni = 0; ni < 4; ++ni) acc[mi][ni] = fzero4();
  const bf16* wb = woutt + (size_t)(n0 + l15) * DIM + g * 8;
  for (int kk = 0; kk < DIM; kk += 32) {
    bf16x8 a[2], b[4];
    #pragma unroll
    for (int mi = 0; mi < 2; ++mi) {
      int rr = mi * 16 + l15;
      a[mi] = *(const bf16x8*)&la[rr][(kk + g * 8) ^ ((rr & 7) << 3)];
    }
    #pragma unroll
    for (int ni = 0; ni < 4; ++ni)
      b[ni] = *(const bf16x8*)(wb + (size_t)ni * 16 * DIM + kk);
    #pragma unroll
    for (int mi = 0; mi < 2; ++mi)
      #pragma unroll
      for (int ni = 0; ni < 4; ++ni)
        acc[mi][ni] = mfma16(a[mi], b[ni], acc[mi][ni]);
  }

  // LN partials: reduce over this wave's 64 cols, then across waves via LDS
  #pragma unroll
  for (int mi = 0; mi < 2; ++mi)
    #pragma unroll
    for (int jj = 0; jj < 4; ++jj) {
      float s = acc[mi][0][jj] + acc[mi][1][jj] + acc[mi][2][jj] + acc[mi][3][jj];
      float q = acc[mi][0][jj]*acc[mi][0][jj] + acc[mi][1][jj]*acc[mi][1][jj]
              + acc[mi][2][jj]*acc[mi][2][jj] + acc[mi][3][jj]*acc[mi][3][jj];
      s += __shfl_xor(s, 1); q += __shfl_xor(q, 1);
      s += __shfl_xor(s, 2); q += __shfl_xor(q, 2);
      s += __shfl_xor(s, 4); q += __shfl_xor(q, 4);
      s += __shfl_xor(s, 8); q += __shfl_xor(q, 8);
      if (l15 == 0) part[mi * 16 + g * 4 + jj][wave] = make_float2(s, q);
    }
  __syncthreads();
  if (t < 32) {
    float S = 0.f, Q = 0.f;
    #pragma unroll
    for (int w = 0; w < 8; ++w) { S += part[t][w].x; Q += part[t][w].y; }
    float mean = S * (1.f / 512.f);
    float var  = Q * (1.f / 512.f) - mean * mean;
    stats[t] = make_float2(mean, rsqrtf(var + 1e-5f));
  }
  __syncthreads();

  #pragma unroll
  for (int mi = 0; mi < 2; ++mi)
    #pragma unroll
    for (int ni = 0; ni < 4; ++ni) {
      int col = n0 + ni * 16 + l15;
      float gg = gout[col];
      #pragma unroll
      for (int jj = 0; jj < 4; ++jj) {
        int row = mi * 16 + g * 4 + jj;
        float2 st = stats[row];
        out[(row0 + row) * DIM + col] = (acc[mi][ni][jj] - st.x) * st.y * gg;
      }
    }
}

// ---------------- launch ----------------
extern "C" void kernel_launch(void* const* d_in, const int* in_sizes, int n_in,
                              void* d_out, int out_size, void* d_ws, size_t ws_size,
                              hipStream_t stream) {
  const float* x     = (const float*)d_in[0];
  const float* gnorm = (const float*)d_in[1];
  const float* Wq    = (const float*)d_in[2];
  const float* Wkv   = (const float*)d_in[3];
  const float* Wout  = (const float*)d_in[4];
  const float* gout  = (const float*)d_in[5];
  float* out = (float*)d_out;
  char* ws = (char*)d_ws;
  // ws layout (bytes): wqt 512K | wkvt 128K | woutt 512K | qbuf 64M | kbuf 8M | vbuf 8M
  bf16* wqt   = (bf16*)(ws);
  bf16* wkvt  = (bf16*)(ws + 524288);
  bf16* woutt = (bf16*)(ws + 655360);
  bf16* qbuf  = (bf16*)(ws + 1179648);
  bf16* kbuf  = (bf16*)((char*)qbuf + (size_t)TOK * DIM * 2);
  bf16* vbuf  = (bf16*)((char*)kbuf + (size_t)TOK * DHEAD * 2);

  k_prep  <<<dim3(1024), dim3(256), 0, stream>>>(Wq, Wkv, Wout, wqt, wkvt, woutt);
  k_ln_qkv<<<dim3(1024), dim3(512), 0, stream>>>(x, gnorm, wqt, wkvt, qbuf, kbuf, vbuf);
  k_attn  <<<dim3(2048), dim3(512), 0, stream>>>(qbuf, kbuf, vbuf);
  k_out_ln<<<dim3(2048), dim3(512), 0, stream>>>(qbuf, woutt, gout, out);
}

// Round 2
// 353.392 us; speedup vs baseline: 1.1550x; 1.1550x over previous
//
#include <hip/hip_runtime.h>

// Fused: LN -> QKV proj -> 8-head attention (flash) -> out proj -> LN
// Shapes: x[4,64,256,512]; heads=8, dhead=64; all GEMMs bf16 MFMA, f32 accum.

#define DIM   512
#define DHEAD 64
#define HEADS 8
#define RLEN  256
#define TOK   65536   // 4*64*256 tokens

typedef __bf16 bf16;
typedef __bf16 bf16x8 __attribute__((ext_vector_type(8)));
typedef float  f32x4  __attribute__((ext_vector_type(4)));

__device__ __forceinline__ f32x4 mfma16(bf16x8 a, bf16x8 b, f32x4 c) {
  return __builtin_amdgcn_mfma_f32_16x16x32_bf16(a, b, c, 0, 0, 0);
}
__device__ __forceinline__ f32x4 fzero4() {
  f32x4 z; z[0] = z[1] = z[2] = z[3] = 0.f; return z;
}

// ---------------- K0: weights -> bf16, transposed to [N][K] ----------------
__global__ __launch_bounds__(256) void k_prep(
    const float* __restrict__ Wq, const float* __restrict__ Wkv,
    const float* __restrict__ Wout,
    bf16* __restrict__ wqt, bf16* __restrict__ wkvt, bf16* __restrict__ woutt) {
  int t = blockIdx.x * 256 + threadIdx.x;   // grid covers exactly 512*512
  int n = t >> 9, k = t & 511;
  wqt[t]   = (bf16)Wq[k * DIM + n];     // wqt[n][k] = W_q[k][n]
  woutt[t] = (bf16)Wout[k * DIM + n];   // woutt[n][k] = W_out[k][n]
  if (t < 128 * DIM) wkvt[t] = (bf16)Wkv[k * 128 + n];  // wkvt[n][k], n<128
}

// ---------------- K1: LN + Q/KV projection ----------------
// 64 token-rows per WG, 512 threads (8 waves). xn in XOR-swizzled LDS.
// K-loop software-pipelined: A(LDS) and B(L2) fragments prefetched one
// 32-K stage ahead in registers (manual 2-stage buffers, static indexing).
__global__ __launch_bounds__(512) void k_ln_qkv(
    const float* __restrict__ x, const float* __restrict__ gnorm,
    const bf16* __restrict__ wqt, const bf16* __restrict__ wkvt,
    bf16* __restrict__ qbuf, bf16* __restrict__ kbuf, bf16* __restrict__ vbuf) {
  __shared__ bf16 xn[64][DIM];  // element index XOR-swizzled by ((row&7)<<3)
  const int t = threadIdx.x;
  const int row0 = blockIdx.x * 64;

  { // ---- LayerNorm: 8 threads per row ----
    const int r = t >> 3, sub = t & 7;
    const float* xp = x + (size_t)(row0 + r) * DIM + sub * 64;
    float4 buf[16];
    float s = 0.f, sq = 0.f;
    #pragma unroll
    for (int i = 0; i < 16; ++i) {
      buf[i] = ((const float4*)xp)[i];
      s  += buf[i].x + buf[i].y + buf[i].z + buf[i].w;
      sq += buf[i].x*buf[i].x + buf[i].y*buf[i].y + buf[i].z*buf[i].z + buf[i].w*buf[i].w;
    }
    s += __shfl_xor(s, 1); sq += __shfl_xor(sq, 1);
    s += __shfl_xor(s, 2); sq += __shfl_xor(sq, 2);
    s += __shfl_xor(s, 4); sq += __shfl_xor(sq, 4);
    float mean = s * (1.f / 512.f);
    float var  = sq * (1.f / 512.f) - mean * mean;
    float rs   = rsqrtf(var + 1e-5f);
    const float* gp = gnorm + sub * 64;
    #pragma unroll
    for (int i = 0; i < 16; i += 2) {
      bf16x8 v8;
      #pragma unroll
      for (int u = 0; u < 2; ++u) {
        float4 bv = buf[i + u];
        v8[u*4+0] = (bf16)((bv.x - mean) * rs * gp[(i+u)*4+0]);
        v8[u*4+1] = (bf16)((bv.y - mean) * rs * gp[(i+u)*4+1]);
        v8[u*4+2] = (bf16)((bv.z - mean) * rs * gp[(i+u)*4+2]);
        v8[u*4+3] = (bf16)((bv.w - mean) * rs * gp[(i+u)*4+3]);
      }
      int c = sub * 64 + i * 4;
      *(bf16x8*)&xn[r][c ^ ((r & 7) << 3)] = v8;
    }
  }

  // ---- GEMM: [64,512] x Wq^T[512n][512k] (+ Wkv^T[128n][512k]) ----
  const int wave = t >> 6, lane = t & 63;
  const int l15 = lane & 15, g = lane >> 4;
  const int n0 = wave * 64;
  const bf16* wq_base  = wqt  + (size_t)(n0 + l15) * DIM + g * 8;
  const bf16* wkv_base = wkvt + (size_t)(wave * 16 + l15) * DIM + g * 8;

  // issue stage-0 B prefetch before the barrier (independent of LDS)
  bf16x8 bqA[4], bqB[4], bkvA, bkvB;
  #pragma unroll
  for (int ni = 0; ni < 4; ++ni)
    bqA[ni] = *(const bf16x8*)(wq_base + (size_t)ni * 16 * DIM);
  bkvA = *(const bf16x8*)(wkv_base);

  __syncthreads();

  f32x4 acc[4][4], acck[4];
  #pragma unroll
  for (int mi = 0; mi < 4; ++mi) {
    acck[mi] = fzero4();
    #pragma unroll
    for (int ni = 0; ni < 4; ++ni) acc[mi][ni] = fzero4();
  }

  bf16x8 aA[4], aB[4];
  #pragma unroll
  for (int mi = 0; mi < 4; ++mi) {
    int rr = mi * 16 + l15;
    aA[mi] = *(const bf16x8*)&xn[rr][(g * 8) ^ ((rr & 7) << 3)];
  }

  for (int kk = 0; kk < DIM; kk += 64) {
    // prefetch stage kk+32
    #pragma unroll
    for (int ni = 0; ni < 4; ++ni)
      bqB[ni] = *(const bf16x8*)(wq_base + (size_t)ni * 16 * DIM + kk + 32);
    bkvB = *(const bf16x8*)(wkv_base + kk + 32);
    #pragma unroll
    for (int mi = 0; mi < 4; ++mi) {
      int rr = mi * 16 + l15;
      aB[mi] = *(const bf16x8*)&xn[rr][(kk + 32 + g * 8) ^ ((rr & 7) << 3)];
    }
    // compute stage kk
    #pragma unroll
    for (int mi = 0; mi < 4; ++mi) {
      #pragma unroll
      for (int ni = 0; ni < 4; ++ni)
        acc[mi][ni] = mfma16(aA[mi], bqA[ni], acc[mi][ni]);
      acck[mi] = mfma16(aA[mi], bkvA, acck[mi]);
    }
    // prefetch stage kk+64
    if (kk + 64 < DIM) {
      #pragma unroll
      for (int ni = 0; ni < 4; ++ni)
        bqA[ni] = *(const bf16x8*)(wq_base + (size_t)ni * 16 * DIM + kk + 64);
      bkvA = *(const bf16x8*)(wkv_base + kk + 64);
      #pragma unroll
      for (int mi = 0; mi < 4; ++mi) {
        int rr = mi * 16 + l15;
        aA[mi] = *(const bf16x8*)&xn[rr][(kk + 64 + g * 8) ^ ((rr & 7) << 3)];
      }
    }
    // compute stage kk+32
    #pragma unroll
    for (int mi = 0; mi < 4; ++mi) {
      #pragma unroll
      for (int ni = 0; ni < 4; ++ni)
        acc[mi][ni] = mfma16(aB[mi], bqB[ni], acc[mi][ni]);
      acck[mi] = mfma16(aB[mi], bkvB, acck[mi]);
    }
  }

  // write q
  #pragma unroll
  for (int mi = 0; mi < 4; ++mi)
    #pragma unroll
    for (int ni = 0; ni < 4; ++ni)
      #pragma unroll
      for (int jj = 0; jj < 4; ++jj) {
        size_t row = (size_t)row0 + mi * 16 + g * 4 + jj;
        qbuf[row * DIM + n0 + ni * 16 + l15] = (bf16)acc[mi][ni][jj];
      }
  // write k/v (cols 0..63 -> k, 64..127 -> v)
  {
    int c = wave * 16 + l15;
    bf16* kvout = (wave < 4) ? (kbuf + c) : (vbuf + (c - 64));
    #pragma unroll
    for (int mi = 0; mi < 4; ++mi)
      #pragma unroll
      for (int jj = 0; jj < 4; ++jj) {
        size_t row = (size_t)row0 + mi * 16 + g * 4 + jj;
        kvout[row * DHEAD] = (bf16)acck[mi][jj];
      }
  }
}

// ---------------- K2: flash attention per (b*n, head) ----------------
// 512 threads (8 waves x 32 q-rows). Q in regs; K, V^T chunk-staged in LDS.
// All LDS tiles XOR-swizzled: col ^ ((row&7)<<3), uniform bank load.
__global__ __launch_bounds__(512) void k_attn(
    bf16* __restrict__ qbuf, const bf16* __restrict__ kbuf,
    const bf16* __restrict__ vbuf) {
  __shared__ bf16 lk[64][64];       // K chunk  [kvrow][d]
  __shared__ bf16 lvt[64][64];      // V^T chunk [d][kvrow]
  __shared__ bf16 lp[8][32][64];    // per-wave P tile [qrow][kvcol]
  const int t = threadIdx.x, wave = t >> 6, lane = t & 63;
  const int l15 = lane & 15, g = lane >> 4;
  const int bn = blockIdx.x >> 3, h = blockIdx.x & 7;
  const size_t tok0 = (size_t)bn * RLEN;
  const int m0 = wave * 32;

  bf16x8 aq[2][2];
  {
    const bf16* qb = qbuf + (tok0 + m0 + l15) * DIM + h * DHEAD + g * 8;
    #pragma unroll
    for (int mi = 0; mi < 2; ++mi)
      #pragma unroll
      for (int ks = 0; ks < 2; ++ks)
        aq[mi][ks] = *(const bf16x8*)(qb + (size_t)mi * 16 * DIM + ks * 32);
  }
  f32x4 o[2][4];
  float mrow[2][4], lrow[2][4];
  #pragma unroll
  for (int mi = 0; mi < 2; ++mi) {
    #pragma unroll
    for (int di = 0; di < 4; ++di) o[mi][di] = fzero4();
    #pragma unroll
    for (int jj = 0; jj < 4; ++jj) { mrow[mi][jj] = -1e30f; lrow[mi][jj] = 0.f; }
  }

  for (int j = 0; j < 4; ++j) {
    __syncthreads();
    { // stage K chunk (coalesced 16B) and V^T chunk
      const bf16* kc = kbuf + (tok0 + j * 64) * DHEAD;
      int r = t >> 3, c8 = (t & 7) * 8;
      *(bf16x8*)&lk[r][c8 ^ ((r & 7) << 3)] = *(const bf16x8*)(kc + r * DHEAD + c8);
      const bf16* vc = vbuf + (tok0 + j * 64) * DHEAD;
      int c = t & 63;
      #pragma unroll
      for (int i = 0; i < 8; ++i) {
        int rr = (t >> 6) + i * 8;
        lvt[c][rr ^ ((c & 7) << 3)] = vc[rr * DHEAD + c];
      }
    }
    __syncthreads();

    // S = Q K^T for this chunk
    f32x4 s[2][4];
    #pragma unroll
    for (int mi = 0; mi < 2; ++mi)
      #pragma unroll
      for (int nj = 0; nj < 4; ++nj) s[mi][nj] = fzero4();
    #pragma unroll
    for (int ks = 0; ks < 2; ++ks) {
      bf16x8 bk[4];
      #pragma unroll
      for (int nj = 0; nj < 4; ++nj)
        bk[nj] = *(const bf16x8*)&lk[nj * 16 + l15][(ks * 32 + g * 8) ^ ((l15 & 7) << 3)];
      #pragma unroll
      for (int mi = 0; mi < 2; ++mi)
        #pragma unroll
        for (int nj = 0; nj < 4; ++nj)
          s[mi][nj] = mfma16(aq[mi][ks], bk[nj], s[mi][nj]);
    }

    // online softmax update (scale = 1/8 folds SCALE*PB_ALPHA)
    #pragma unroll
    for (int mi = 0; mi < 2; ++mi) {
      #pragma unroll
      for (int jj = 0; jj < 4; ++jj) {
        float s0 = s[mi][0][jj] * 0.125f;
        float s1 = s[mi][1][jj] * 0.125f;
        float s2 = s[mi][2][jj] * 0.125f;
        float s3 = s[mi][3][jj] * 0.125f;
        float cm = fmaxf(fmaxf(s0, s1), fmaxf(s2, s3));
        cm = fmaxf(cm, __shfl_xor(cm, 1));
        cm = fmaxf(cm, __shfl_xor(cm, 2));
        cm = fmaxf(cm, __shfl_xor(cm, 4));
        cm = fmaxf(cm, __shfl_xor(cm, 8));
        float mold = mrow[mi][jj];
        float mnew = fmaxf(mold, cm);
        float alpha = __expf(mold - mnew);
        mrow[mi][jj] = mnew;
        float p0 = __expf(s0 - mnew), p1 = __expf(s1 - mnew);
        float p2 = __expf(s2 - mnew), p3 = __expf(s3 - mnew);
        float ps = p0 + p1 + p2 + p3;
        ps += __shfl_xor(ps, 1); ps += __shfl_xor(ps, 2);
        ps += __shfl_xor(ps, 4); ps += __shfl_xor(ps, 8);
        lrow[mi][jj] = lrow[mi][jj] * alpha + ps;
        #pragma unroll
        for (int di = 0; di < 4; ++di) o[mi][di][jj] *= alpha;
        int prow = mi * 16 + g * 4 + jj;
        int sw = (prow & 7) << 3;
        lp[wave][prow][( 0 + l15) ^ sw] = (bf16)p0;
        lp[wave][prow][(16 + l15) ^ sw] = (bf16)p1;
        lp[wave][prow][(32 + l15) ^ sw] = (bf16)p2;
        lp[wave][prow][(48 + l15) ^ sw] = (bf16)p3;
      }
    }
    __syncthreads();

    // O += P V
    #pragma unroll
    for (int ks = 0; ks < 2; ++ks) {
      bf16x8 pa[2], bv[4];
      #pragma unroll
      for (int mi = 0; mi < 2; ++mi)
        pa[mi] = *(const bf16x8*)&lp[wave][mi * 16 + l15][(ks * 32 + g * 8) ^ ((l15 & 7) << 3)];
      #pragma unroll
      for (int di = 0; di < 4; ++di)
        bv[di] = *(const bf16x8*)&lvt[di * 16 + l15][(ks * 32 + g * 8) ^ ((l15 & 7) << 3)];
      #pragma unroll
      for (int mi = 0; mi < 2; ++mi)
        #pragma unroll
        for (int di = 0; di < 4; ++di)
          o[mi][di] = mfma16(pa[mi], bv[di], o[mi][di]);
    }
  }

  // epilogue: normalize, write back in place
  #pragma unroll
  for (int mi = 0; mi < 2; ++mi)
    #pragma unroll
    for (int jj = 0; jj < 4; ++jj) {
      float inv = 1.0f / lrow[mi][jj];
      size_t row = tok0 + m0 + mi * 16 + g * 4 + jj;
      #pragma unroll
      for (int di = 0; di < 4; ++di)
        qbuf[row * DIM + h * DHEAD + di * 16 + l15] = (bf16)(o[mi][di][jj] * inv);
    }
}

// ---------------- K3: out projection + LN ----------------
// 64 token-rows per WG, 512 threads (8 waves x 64 cols), pipelined K-loop.
__global__ __launch_bounds__(512) void k_out_ln(
    const bf16* __restrict__ abuf, const bf16* __restrict__ woutt,
    const float* __restrict__ gout, float* __restrict__ out) {
  __shared__ bf16 la[64][DIM];     // XOR-swizzled
  __shared__ float2 part[64][8];
  __shared__ float2 stats[64];
  const int t = threadIdx.x, wave = t >> 6, lane = t & 63;
  const int l15 = lane & 15, g = lane >> 4;
  const size_t row0 = (size_t)blockIdx.x * 64;
  const int n0 = wave * 64;
  const bf16* wb = woutt + (size_t)(n0 + l15) * DIM + g * 8;

  // stage-0 B prefetch before staging barrier
  bf16x8 bA[4], bB[4];
  #pragma unroll
  for (int ni = 0; ni < 4; ++ni)
    bA[ni] = *(const bf16x8*)(wb + (size_t)ni * 16 * DIM);

  #pragma unroll
  for (int u = 0; u < 8; ++u) {
    int idx = u * 512 + t;
    int r = idx >> 6, c = (idx & 63) * 8;
    *(bf16x8*)&la[r][c ^ ((r & 7) << 3)] =
        *(const bf16x8*)(abuf + (row0 + r) * DIM + c);
  }
  __syncthreads();

  f32x4 acc[4][4];
  #pragma unroll
  for (int mi = 0; mi < 4; ++mi)
    #pragma unroll
    for (int ni = 0; ni < 4; ++ni) acc[mi][ni] = fzero4();

  bf16x8 aA[4], aB[4];
  #pragma unroll
  for (int mi = 0; mi < 4; ++mi) {
    int rr = mi * 16 + l15;
    aA[mi] = *(const bf16x8*)&la[rr][(g * 8) ^ ((rr & 7) << 3)];
  }

  for (int kk = 0; kk < DIM; kk += 64) {
    #pragma unroll
    for (int ni = 0; ni < 4; ++ni)
      bB[ni] = *(const bf16x8*)(wb + (size_t)ni * 16 * DIM + kk + 32);
    #pragma unroll
    for (int mi = 0; mi < 4; ++mi) {
      int rr = mi * 16 + l15;
      aB[mi] = *(const bf16x8*)&la[rr][(kk + 32 + g * 8) ^ ((rr & 7) << 3)];
    }
    #pragma unroll
    for (int mi = 0; mi < 4; ++mi)
      #pragma unroll
      for (int ni = 0; ni < 4; ++ni)
        acc[mi][ni] = mfma16(aA[mi], bA[ni], acc[mi][ni]);
    if (kk + 64 < DIM) {
      #pragma unroll
      for (int ni = 0; ni < 4; ++ni)
        bA[ni] = *(const bf16x8*)(wb + (size_t)ni * 16 * DIM + kk + 64);
      #pragma unroll
      for (int mi = 0; mi < 4; ++mi) {
        int rr = mi * 16 + l15;
        aA[mi] = *(const bf16x8*)&la[rr][(kk + 64 + g * 8) ^ ((rr & 7) << 3)];
      }
    }
    #pragma unroll
    for (int mi = 0; mi < 4; ++mi)
      #pragma unroll
      for (int ni = 0; ni < 4; ++ni)
        acc[mi][ni] = mfma16(aB[mi], bB[ni], acc[mi][ni]);
  }

  // LN partials: reduce over this wave's 64 cols, then across waves via LDS
  #pragma unroll
  for (int mi = 0; mi < 4; ++mi)
    #pragma unroll
    for (int jj = 0; jj < 4; ++jj) {
      float s = acc[mi][0][jj] + acc[mi][1][jj] + acc[mi][2][jj] + acc[mi][3][jj];
      float q = acc[mi][0][jj]*acc[mi][0][jj] + acc[mi][1][jj]*acc[mi][1][jj]
              + acc[mi][2][jj]*acc[mi][2][jj] + acc[mi][3][jj]*acc[mi][3][jj];
      s += __shfl_xor(s, 1); q += __shfl_xor(q, 1);
      s += __shfl_xor(s, 2); q += __shfl_xor(q, 2);
      s += __shfl_xor(s, 4); q += __shfl_xor(q, 4);
      s += __shfl_xor(s, 8); q += __shfl_xor(q, 8);
      if (l15 == 0) part[mi * 16 + g * 4 + jj][wave] = make_float2(s, q);
    }
  __syncthreads();
  if (t < 64) {
    float S = 0.f, Q = 0.f;
    #pragma unroll
    for (int w = 0; w < 8; ++w) { S += part[t][w].x; Q += part[t][w].y; }
    float mean = S * (1.f / 512.f);
    float var  = Q * (1.f / 512.f) - mean * mean;
    stats[t] = make_float2(mean, rsqrtf(var + 1e-5f));
  }
  __syncthreads();

  #pragma unroll
  for (int mi = 0; mi < 4; ++mi)
    #pragma unroll
    for (int ni = 0; ni < 4; ++ni) {
      int col = n0 + ni * 16 + l15;
      float gg = gout[col];
      #pragma unroll
      for (int jj = 0; jj < 4; ++jj) {
        int row = mi * 16 + g * 4 + jj;
        float2 st = stats[row];
        out[(row0 + row) * DIM + col] = (acc[mi][ni][jj] - st.x) * st.y * gg;
      }
    }
}

// ---------------- launch ----------------
extern "C" void kernel_launch(void* const* d_in, const int* in_sizes, int n_in,
                              void* d_out, int out_size, void* d_ws, size_t ws_size,
                              hipStream_t stream) {
  const float* x     = (const float*)d_in[0];
  const float* gnorm = (const float*)d_in[1];
  const float* Wq    = (const float*)d_in[2];
  const float* Wkv   = (const float*)d_in[3];
  const float* Wout  = (const float*)d_in[4];
  const float* gout  = (const float*)d_in[5];
  float* out = (float*)d_out;
  char* ws = (char*)d_ws;
  // ws layout (bytes): wqt 512K | wkvt 128K | woutt 512K | qbuf 64M | kbuf 8M | vbuf 8M
  bf16* wqt   = (bf16*)(ws);
  bf16* wkvt  = (bf16*)(ws + 524288);
  bf16* woutt = (bf16*)(ws + 655360);
  bf16* qbuf  = (bf16*)(ws + 1179648);
  bf16* kbuf  = (bf16*)((char*)qbuf + (size_t)TOK * DIM * 2);
  bf16* vbuf  = (bf16*)((char*)kbuf + (size_t)TOK * DHEAD * 2);

  k_prep  <<<dim3(1024), dim3(256), 0, stream>>>(Wq, Wkv, Wout, wqt, wkvt, woutt);
  k_ln_qkv<<<dim3(1024), dim3(512), 0, stream>>>(x, gnorm, wqt, wkvt, qbuf, kbuf, vbuf);
  k_attn  <<<dim3(2048), dim3(512), 0, stream>>>(qbuf, kbuf, vbuf);
  k_out_ln<<<dim3(1024), dim3(512), 0, stream>>>(qbuf, woutt, gout, out);
}